// Round 5
// baseline (68.060 us; speedup 1.0000x reference)
//
#include <hip/hip_runtime.h>
#include <stdint.h>

// out[b,i] = x[b,i] * (sum_j x[b,j] * W[i,j]) + bias[i]
// Two-phase: (1) convert X,W fp32->bf16 once into ws;
// (2) LDS-free MFMA GEMM: 256-thread blocks, 4 waves in 2x2 -> 64x64 block
// tile (waves share A/B lines via L1), each wave 32x32 via 2x2 16x16x32
// bf16 fragments with 4 independent accumulator chains, fused fp32 epilogue.

#define LATENT 512
#define BATCH  1024
#define XN (BATCH * LATENT)    // 524288 floats
#define WN (LATENT * LATENT)   // 262144 floats

typedef short bf16x8 __attribute__((ext_vector_type(8)));   // 8 bf16, 4 VGPRs
typedef float f32x4  __attribute__((ext_vector_type(4)));

__device__ __forceinline__ short f2bf(float f) {
    // RNE fp32 -> bf16 (finite normals)
    uint32_t u = __builtin_bit_cast(uint32_t, f);
    u += 0x7FFFu + ((u >> 16) & 1u);
    return (short)(u >> 16);
}

// ---- Kernel 1: convert X and W to bf16 in ws (each element exactly once) ----
__global__ __launch_bounds__(256) void convert_kernel(
    const float* __restrict__ X, const float* __restrict__ W,
    short* __restrict__ Xb, short* __restrict__ Wb)
{
    const int g = (blockIdx.x * 256 + threadIdx.x) * 8;
    const float* src;
    short* dst;
    if (g < XN) { src = X + g;        dst = Xb + g; }
    else        { src = W + (g - XN); dst = Wb + (g - XN); }
    f32x4 v0 = ((const f32x4*)src)[0];
    f32x4 v1 = ((const f32x4*)src)[1];
    short s[8];
    #pragma unroll
    for (int i = 0; i < 4; ++i) s[i]     = f2bf(v0[i]);
    #pragma unroll
    for (int i = 0; i < 4; ++i) s[4 + i] = f2bf(v1[i]);
    *(bf16x8*)dst = *(bf16x8*)s;
}

// ---- Kernel 2: GEMM C = Xb · Wb^T, 64x64 block tile / 32x32 wave tile ----
// A[m=lane&15][k=q*8+j], B[n=lane&15][k=q*8+j]; rows K-contiguous bf16.
// C/D frag: col = lane&15, row = q*4 + reg.
__global__ __launch_bounds__(256) void gemm_kernel(
    const short* __restrict__ Xb, const short* __restrict__ Wb,
    const float* __restrict__ X, const float* __restrict__ bias,
    float* __restrict__ out)
{
    const int tid  = threadIdx.x;
    const int lane = tid & 63;
    const int wv   = tid >> 6;                      // 0..3, 2x2 wave grid
    const int m0   = blockIdx.y * 64 + (wv >> 1) * 32;
    const int n0   = blockIdx.x * 64 + (wv & 1) * 32;
    const int lrow = lane & 15;
    const int q    = lane >> 4;                     // 0..3

    const short* ap0 = Xb + (size_t)(m0 + lrow) * LATENT + q * 8;
    const short* ap1 = ap0 + 16 * LATENT;
    const short* bp0 = Wb + (size_t)(n0 + lrow) * LATENT + q * 8;
    const short* bp1 = bp0 + 16 * LATENT;

    f32x4 acc[2][2] = {};
    #pragma unroll
    for (int ks = 0; ks < 16; ++ks) {
        bf16x8 a0 = *(const bf16x8*)(ap0 + ks * 32);   // 64B imm offsets
        bf16x8 a1 = *(const bf16x8*)(ap1 + ks * 32);
        bf16x8 b0 = *(const bf16x8*)(bp0 + ks * 32);
        bf16x8 b1 = *(const bf16x8*)(bp1 + ks * 32);
        acc[0][0] = __builtin_amdgcn_mfma_f32_16x16x32_bf16(a0, b0, acc[0][0], 0, 0, 0);
        acc[0][1] = __builtin_amdgcn_mfma_f32_16x16x32_bf16(a0, b1, acc[0][1], 0, 0, 0);
        acc[1][0] = __builtin_amdgcn_mfma_f32_16x16x32_bf16(a1, b0, acc[1][0], 0, 0, 0);
        acc[1][1] = __builtin_amdgcn_mfma_f32_16x16x32_bf16(a1, b1, acc[1][1], 0, 0, 0);
    }

    // Epilogue in fp32: out = x * wx + bias
    #pragma unroll
    for (int mi = 0; mi < 2; ++mi) {
        #pragma unroll
        for (int ni = 0; ni < 2; ++ni) {
            #pragma unroll
            for (int r = 0; r < 4; ++r) {
                const int m = m0 + mi * 16 + q * 4 + r;
                const int n = n0 + ni * 16 + lrow;
                out[(size_t)m * LATENT + n] =
                    X[(size_t)m * LATENT + n] * acc[mi][ni][r] + bias[n];
            }
        }
    }
}

extern "C" void kernel_launch(void* const* d_in, const int* in_sizes, int n_in,
                              void* d_out, int out_size, void* d_ws, size_t ws_size,
                              hipStream_t stream) {
    const float* X    = (const float*)d_in[0];   // (1024, 512)
    const float* W    = (const float*)d_in[1];   // (512, 512)
    const float* bias = (const float*)d_in[2];   // (512,)
    float* out        = (float*)d_out;           // (1024, 512)

    short* Xb = (short*)d_ws;                    // 1 MiB
    short* Wb = (short*)d_ws + XN;               // 512 KiB

    convert_kernel<<<(XN + WN) / 8 / 256, 256, 0, stream>>>(X, W, Xb, Wb);
    gemm_kernel<<<dim3(LATENT / 64, BATCH / 64), 256, 0, stream>>>(Xb, Wb, X, bias, out);
}

// Round 6
// 63.408 us; speedup vs baseline: 1.0734x; 1.0734x over previous
//
#include <hip/hip_runtime.h>
#include <stdint.h>

// out[b,i] = x[b,i] * (sum_j x[b,j] * W[i,j]) + bias[i]
// Two-phase (R4 structure — best measured: 63.7 us):
// (1) convert X,W fp32->bf16 once into ws;
// (2) LDS-free MFMA GEMM, one 64-thread block (1 wave) per 32x32 output
//     tile -> 512 blocks = full 256-CU coverage at 2 waves/CU. Each wave:
//     2x2 16x16x32 bf16 fragments, 4 independent accumulator chains,
//     direct global->register loads (inputs fit in every XCD L2: 1.5 MB),
//     fused fp32 epilogue.
// R5 lesson: 64x64 block tiles -> 128 blocks -> half the CUs idle. Tile
// count (not reuse) is the binding constraint at this problem size.

#define LATENT 512
#define BATCH  1024
#define XN (BATCH * LATENT)    // 524288 floats
#define WN (LATENT * LATENT)   // 262144 floats

typedef short bf16x8 __attribute__((ext_vector_type(8)));   // 8 bf16, 4 VGPRs
typedef float f32x4  __attribute__((ext_vector_type(4)));

__device__ __forceinline__ short f2bf(float f) {
    // RNE fp32 -> bf16 (finite normals)
    uint32_t u = __builtin_bit_cast(uint32_t, f);
    u += 0x7FFFu + ((u >> 16) & 1u);
    return (short)(u >> 16);
}

// ---- Kernel 1: convert X and W to bf16 in ws (each element exactly once) ----
__global__ __launch_bounds__(256) void convert_kernel(
    const float* __restrict__ X, const float* __restrict__ W,
    short* __restrict__ Xb, short* __restrict__ Wb)
{
    const int g = (blockIdx.x * 256 + threadIdx.x) * 8;
    const float* src;
    short* dst;
    if (g < XN) { src = X + g;        dst = Xb + g; }
    else        { src = W + (g - XN); dst = Wb + (g - XN); }
    f32x4 v0 = ((const f32x4*)src)[0];
    f32x4 v1 = ((const f32x4*)src)[1];
    short s[8];
    #pragma unroll
    for (int i = 0; i < 4; ++i) s[i]     = f2bf(v0[i]);
    #pragma unroll
    for (int i = 0; i < 4; ++i) s[4 + i] = f2bf(v1[i]);
    *(bf16x8*)dst = *(bf16x8*)s;
}

// ---- Kernel 2: GEMM C = Xb · Wb^T, 32x32 per wave, fused epilogue ----
// A[m=lane&15][k=q*8+j], B[n=lane&15][k=q*8+j]; rows K-contiguous bf16.
// C/D frag: col = lane&15, row = q*4 + reg.
__global__ __launch_bounds__(64) void gemm_kernel(
    const short* __restrict__ Xb, const short* __restrict__ Wb,
    const float* __restrict__ X, const float* __restrict__ bias,
    float* __restrict__ out)
{
    const int lane = threadIdx.x;       // one wave per block
    const int m0   = blockIdx.y * 32;
    const int n0   = blockIdx.x * 32;
    const int lrow = lane & 15;
    const int q    = lane >> 4;         // 0..3

    const short* ap0 = Xb + (size_t)(m0 + lrow) * LATENT + q * 8;
    const short* ap1 = ap0 + 16 * LATENT;
    const short* bp0 = Wb + (size_t)(n0 + lrow) * LATENT + q * 8;
    const short* bp1 = bp0 + 16 * LATENT;

    f32x4 acc[2][2] = {};
    #pragma unroll
    for (int ks = 0; ks < 16; ++ks) {
        bf16x8 a0 = *(const bf16x8*)(ap0 + ks * 32);   // 64B imm offsets
        bf16x8 a1 = *(const bf16x8*)(ap1 + ks * 32);
        bf16x8 b0 = *(const bf16x8*)(bp0 + ks * 32);
        bf16x8 b1 = *(const bf16x8*)(bp1 + ks * 32);
        acc[0][0] = __builtin_amdgcn_mfma_f32_16x16x32_bf16(a0, b0, acc[0][0], 0, 0, 0);
        acc[0][1] = __builtin_amdgcn_mfma_f32_16x16x32_bf16(a0, b1, acc[0][1], 0, 0, 0);
        acc[1][0] = __builtin_amdgcn_mfma_f32_16x16x32_bf16(a1, b0, acc[1][0], 0, 0, 0);
        acc[1][1] = __builtin_amdgcn_mfma_f32_16x16x32_bf16(a1, b1, acc[1][1], 0, 0, 0);
    }

    // Epilogue in fp32: out = x * wx + bias
    #pragma unroll
    for (int mi = 0; mi < 2; ++mi) {
        #pragma unroll
        for (int ni = 0; ni < 2; ++ni) {
            #pragma unroll
            for (int r = 0; r < 4; ++r) {
                const int m = m0 + mi * 16 + q * 4 + r;
                const int n = n0 + ni * 16 + lrow;
                out[(size_t)m * LATENT + n] =
                    X[(size_t)m * LATENT + n] * acc[mi][ni][r] + bias[n];
            }
        }
    }
}

extern "C" void kernel_launch(void* const* d_in, const int* in_sizes, int n_in,
                              void* d_out, int out_size, void* d_ws, size_t ws_size,
                              hipStream_t stream) {
    const float* X    = (const float*)d_in[0];   // (1024, 512)
    const float* W    = (const float*)d_in[1];   // (512, 512)
    const float* bias = (const float*)d_in[2];   // (512,)
    float* out        = (float*)d_out;           // (1024, 512)

    short* Xb = (short*)d_ws;                    // 1 MiB
    short* Wb = (short*)d_ws + XN;               // 512 KiB

    convert_kernel<<<(XN + WN) / 8 / 256, 256, 0, stream>>>(X, W, Xb, Wb);
    gemm_kernel<<<dim3(LATENT / 32, BATCH / 32), 64, 0, stream>>>(Xb, Wb, X, bias, out);
}